// Round 5
// baseline (489.869 us; speedup 1.0000x reference)
//
#include <hip/hip_runtime.h>

// EdgeAttention fused kernel for MI355X (gfx950) — round 5.
// Goal: 2 blocks/CU (4 waves/SIMD). One workgroup (512 thr = 8 waves) per
// (b,l). LDS holds only K (64 KB); V2^T goes to a per-(b,l) global workspace
// slice written in phase 1 and read back (L2-hot, same CU) in phase 2.
// 1-deep half loop keeps the live set <= ~110 regs so two 8-wave blocks fit
// the 2048-reg SIMD pool. All transposes are register shuffles (round-3
// verified); softmax is lane-local via the swapped S^T = mfma(K, Q) layout.
// MFMA layouts (m89/m91/m120-verified):
//   A/B-frag: elem[j] = X[row = lane&15][k = (lane>>4)*8 + j]
//   C/D     : c[r] = D[m = (lane>>4)*4 + r][n = lane&15]
//   (m-axis = FIRST operand's rows, n-axis = second's.)

typedef __bf16 bf16x8 __attribute__((ext_vector_type(8)));
typedef float  f32x4  __attribute__((ext_vector_type(4)));
typedef unsigned short u16x4 __attribute__((ext_vector_type(4)));

#define MFMA(a, b, c) __builtin_amdgcn_mfma_f32_16x16x32_bf16((a), (b), (c), 0, 0, 0)

union U8 { bf16x8 v; unsigned int w[4]; };

// workspace layout: 81920 shorts of bf16 weights, then 512 V2^T slices
// (d-major: elem (j,d) at d*256 + j), 32768 shorts each.
#define WS_V2T 81920
static const size_t WS_NEEDED = (81920ull + 512ull * 32768ull) * 2ull;  // bytes

__device__ __forceinline__ unsigned short rne_bf16(float f) {
  unsigned int u = __float_as_uint(f);
  u += 0x7fffu + ((u >> 16) & 1u);   // round-to-nearest-even
  return (unsigned short)(u >> 16);
}

__device__ __forceinline__ unsigned int cvt_pk(float lo, float hi) {
  unsigned int r;
  asm("v_cvt_pk_bf16_f32 %0, %1, %2" : "=v"(r) : "v"(lo), "v"(hi));
  return r;
}

__device__ __forceinline__ bf16x8 cvt_frag(const float* __restrict__ p) {
  f32x4 a = *(const f32x4*)p;
  f32x4 b = *(const f32x4*)(p + 4);
  U8 t;
  t.w[0] = cvt_pk(a[0], a[1]);
  t.w[1] = cvt_pk(a[2], a[3]);
  t.w[2] = cvt_pk(b[0], b[1]);
  t.w[3] = cvt_pk(b[2], b[3]);
  return t.v;
}

// cross-q4 transpose (round-3 verified): C-layout packed pairs -> A/B-frag.
__device__ __forceinline__ bf16x8 xpose(unsigned int w01a, unsigned int w01b,
                                        unsigned int w23a, unsigned int w23b,
                                        int sa, int sb, bool hi) {
  U8 u;
  { int x0 = __shfl((int)w01a, sa), x1 = __shfl((int)w01b, sa);
    u.w[0] = (unsigned int)(hi ? x1 : x0); }
  { int x0 = __shfl((int)w23a, sa), x1 = __shfl((int)w23b, sa);
    u.w[1] = (unsigned int)(hi ? x1 : x0); }
  { int x0 = __shfl((int)w01a, sb), x1 = __shfl((int)w01b, sb);
    u.w[2] = (unsigned int)(hi ? x1 : x0); }
  { int x0 = __shfl((int)w23a, sb), x1 = __shfl((int)w23b, sb);
    u.w[3] = (unsigned int)(hi ? x1 : x0); }
  return u.v;
}

// lane-local softmax over j (round-3 verified): ST = S^T c-frags (j on
// q4-axis/regs, i on lc). Normalizes and packs to bf16 pair words.
__device__ __forceinline__ void softmax_pack(f32x4 ST[16], unsigned int p01[16],
                                             unsigned int p23[16]) {
  float t16[16];
  #pragma unroll
  for (int jt = 0; jt < 16; ++jt)
    t16[jt] = fmaxf(fmaxf(ST[jt][0], ST[jt][1]), fmaxf(ST[jt][2], ST[jt][3]));
  #pragma unroll
  for (int s = 8; s >= 1; s >>= 1)
    #pragma unroll
    for (int k = 0; k < 16; ++k) if (k < s) t16[k] = fmaxf(t16[k], t16[k + s]);
  float mx = t16[0];
  mx = fmaxf(mx, __shfl_xor(mx, 16));
  mx = fmaxf(mx, __shfl_xor(mx, 32));

  float s16[16];
  #pragma unroll
  for (int jt = 0; jt < 16; ++jt) {
    float e0 = __expf(ST[jt][0] - mx);
    float e1 = __expf(ST[jt][1] - mx);
    float e2 = __expf(ST[jt][2] - mx);
    float e3 = __expf(ST[jt][3] - mx);
    ST[jt][0] = e0; ST[jt][1] = e1; ST[jt][2] = e2; ST[jt][3] = e3;
    s16[jt] = (e0 + e1) + (e2 + e3);
  }
  #pragma unroll
  for (int s = 8; s >= 1; s >>= 1)
    #pragma unroll
    for (int k = 0; k < 16; ++k) if (k < s) s16[k] += s16[k + s];
  float sm = s16[0];
  sm += __shfl_xor(sm, 16);
  sm += __shfl_xor(sm, 32);
  const float inv = 1.0f / sm;

  #pragma unroll
  for (int jt = 0; jt < 16; ++jt) {
    p01[jt] = cvt_pk(ST[jt][0] * inv, ST[jt][1] * inv);
    p23[jt] = cvt_pk(ST[jt][2] * inv, ST[jt][3] * inv);
  }
}

// Setup: convert the 5 weight matrices fp32 -> bf16 into d_ws.
__global__ void cvt_weights(const float* __restrict__ Wq, const float* __restrict__ Wk,
                            const float* __restrict__ Wv1, const float* __restrict__ Wv2,
                            const float* __restrict__ Wo, unsigned short* __restrict__ ws) {
  int t = blockIdx.x * 256 + threadIdx.x;   // 0..16383
  ws[t]             = rne_bf16(Wq[t]);
  ws[16384 + t]     = rne_bf16(Wk[t]);
  ws[2 * 16384 + t] = rne_bf16(Wv1[t]);
  ws[3 * 16384 + t] = rne_bf16(Wv2[t]);
  ws[4 * 16384 + t] = rne_bf16(Wo[t]);
}

// ---------------------------------------------------------------------------
// Round-5 kernel: 64 KB LDS, lean registers, V2^T via workspace slice.
// ---------------------------------------------------------------------------
__global__ __launch_bounds__(512, 4)
void edge_attn_kernel(const float* __restrict__ ef,
                      unsigned short* __restrict__ ws,
                      const float* __restrict__ bq, const float* __restrict__ bk,
                      const float* __restrict__ bv1, const float* __restrict__ bv2,
                      const float* __restrict__ bo,
                      float* __restrict__ out) {
  // K rows (j-major) swizzled: elem (j,o) at j*128 + (((o>>3) ^ (j&15))<<3) + (o&7)
  __shared__ unsigned short Kb[256 * 128];   // 64 KB — the only LDS

  const int tid  = threadIdx.x;
  const int lane = tid & 63;
  const int wv   = tid >> 6;    // wave 0..7
  const int lc   = lane & 15;
  const int q4   = lane >> 4;
  const int bb   = blockIdx.x >> 8;
  const int lb   = blockIdx.x & 255;

  const unsigned short* WqB  = ws;
  const unsigned short* WkB  = ws + 16384;
  const unsigned short* Wv1B = ws + 2 * 16384;
  const unsigned short* Wv2B = ws + 3 * 16384;
  const unsigned short* WoB  = ws + 4 * 16384;
  unsigned short* vsl = ws + WS_V2T + ((size_t)(bb * 256 + lb)) * 32768;

  const f32x4 Z4 = {0.f, 0.f, 0.f, 0.f};
  const int jA = wv * 16;         // phase-1 j-tile A
  const int jB = wv * 16 + 128;   // phase-1 j-tile B

  // ---------------- Phase 1: K -> LDS, V2^T -> workspace slice --------------
  {
    const float* Frow = ef + ((size_t)(bb * 256 + lb)) * (256 * 128);
    bf16x8 aFA[4], aFB[4];
    {
      const float* rpA = Frow + (jA + lc) * 128 + q4 * 8;
      const float* rpB = Frow + (jB + lc) * 128 + q4 * 8;
      #pragma unroll
      for (int kc = 0; kc < 4; ++kc) {
        aFA[kc] = cvt_frag(rpA + kc * 32);
        aFB[kc] = cvt_frag(rpB + kc * 32);
      }
    }

    // K pass (acc pair A/B only — 64 regs)
    {
      f32x4 kA[8], kB[8];
      #pragma unroll
      for (int n = 0; n < 8; ++n) { kA[n] = Z4; kB[n] = Z4; }
      #pragma unroll
      for (int kc = 0; kc < 4; ++kc) {
        #pragma unroll
        for (int n = 0; n < 8; ++n) {
          bf16x8 bwk = *(const bf16x8*)(WkB + (n * 16 + lc) * 128 + kc * 32 + q4 * 8);
          kA[n] = MFMA(aFA[kc], bwk, kA[n]);
          kB[n] = MFMA(aFB[kc], bwk, kB[n]);
        }
      }
      #pragma unroll
      for (int n = 0; n < 8; ++n) {
        const int o = n * 16 + lc;
        const float bkv = bk[o];
        #pragma unroll
        for (int r = 0; r < 4; ++r) {
          const int ja = jA + q4 * 4 + r;
          const int jb = jB + q4 * 4 + r;
          Kb[ja * 128 + (((o >> 3) ^ (ja & 15)) << 3) + (o & 7)] = rne_bf16(kA[n][r] + bkv);
          Kb[jb * 128 + (((o >> 3) ^ (jb & 15)) << 3) + (o & 7)] = rne_bf16(kB[n][r] + bkv);
        }
      }
    }

    // V2 pass (reuses aF; acc pair again 64 regs; j-contig 8B stores)
    {
      f32x4 vA[8], vB[8];
      #pragma unroll
      for (int n = 0; n < 8; ++n) { vA[n] = Z4; vB[n] = Z4; }
      #pragma unroll
      for (int kc = 0; kc < 4; ++kc) {
        #pragma unroll
        for (int n = 0; n < 8; ++n) {
          bf16x8 bwv = *(const bf16x8*)(Wv2B + (n * 16 + lc) * 128 + kc * 32 + q4 * 8);
          vA[n] = MFMA(aFA[kc], bwv, vA[n]);
          vB[n] = MFMA(aFB[kc], bwv, vB[n]);
        }
      }
      #pragma unroll
      for (int n = 0; n < 8; ++n) {
        const int o = n * 16 + lc;            // output channel = d
        const float bvv = bv2[o];
        u16x4 pkA, pkB;
        #pragma unroll
        for (int r = 0; r < 4; ++r) {
          pkA[r] = rne_bf16(vA[n][r] + bvv);
          pkB[r] = rne_bf16(vB[n][r] + bvv);
        }
        *(u16x4*)(vsl + o * 256 + jA + q4 * 4) = pkA;
        *(u16x4*)(vsl + o * 256 + jB + q4 * 4) = pkB;
      }
    }
  }

  // Prefetch h=0 E rows; barrier's vmcnt drain hides the gather latency and
  // makes the V2^T slice stores L2-visible to this CU.
  f32x4 e0[8];
  {
    const float* rp = ef + (((size_t)(bb * 256 + wv * 16 + lc)) * 256 + lb) * 128 + q4 * 8;
    #pragma unroll
    for (int kc = 0; kc < 4; ++kc) {
      e0[2 * kc]     = *(const f32x4*)(rp + kc * 32);
      e0[2 * kc + 1] = *(const f32x4*)(rp + kc * 32 + 4);
    }
  }
  __syncthreads();

  // ---------------- Phase 2: per-wave i-tiles, 1-deep, two halves -----------
  const float scale = 0.08838834764831845f;  // 1/sqrt(128)
  const int sa = ((2 * q4) & 3) * 16 + lc;
  const int sb = ((2 * q4 + 1) & 3) * 16 + lc;
  const bool hi = (q4 >= 2);

  #pragma unroll
  for (int h = 0; h < 2; ++h) {
    const int i0 = wv * 16 + h * 128;

    // E rows for this half (h=0 uses the prefetch)
    bf16x8 aE[4];
    {
      f32x4 eH[8];
      if (h == 0) {
        #pragma unroll
        for (int k = 0; k < 8; ++k) eH[k] = e0[k];
      } else {
        const float* rp = ef + (((size_t)(bb * 256 + i0 + lc)) * 256 + lb) * 128 + q4 * 8;
        #pragma unroll
        for (int kc = 0; kc < 4; ++kc) {
          eH[2 * kc]     = *(const f32x4*)(rp + kc * 32);
          eH[2 * kc + 1] = *(const f32x4*)(rp + kc * 32 + 4);
        }
      }
      #pragma unroll
      for (int kc = 0; kc < 4; ++kc) {
        U8 u;
        u.w[0] = cvt_pk(eH[2 * kc][0], eH[2 * kc][1]);
        u.w[1] = cvt_pk(eH[2 * kc][2], eH[2 * kc][3]);
        u.w[2] = cvt_pk(eH[2 * kc + 1][0], eH[2 * kc + 1][1]);
        u.w[3] = cvt_pk(eH[2 * kc + 1][2], eH[2 * kc + 1][3]);
        aE[kc] = u.v;
      }
    }

    // Q^T projection: Qt[nt] c[r] = Q[i=lc][o = nt*16 + q4*4 + r]
    bf16x8 bQ[4];
    {
      f32x4 Qt[8];
      #pragma unroll
      for (int nt = 0; nt < 8; ++nt) Qt[nt] = Z4;
      #pragma unroll
      for (int kc = 0; kc < 4; ++kc) {
        #pragma unroll
        for (int nt = 0; nt < 8; ++nt) {
          bf16x8 aW = *(const bf16x8*)(WqB + (nt * 16 + lc) * 128 + kc * 32 + q4 * 8);
          Qt[nt] = MFMA(aW, aE[kc], Qt[nt]);
        }
      }
      unsigned int q01[8], q23[8];
      #pragma unroll
      for (int nt = 0; nt < 8; ++nt) {
        f32x4 b4 = *(const f32x4*)(bq + nt * 16 + q4 * 4);
        q01[nt] = cvt_pk((Qt[nt][0] + b4[0]) * scale, (Qt[nt][1] + b4[1]) * scale);
        q23[nt] = cvt_pk((Qt[nt][2] + b4[2]) * scale, (Qt[nt][3] + b4[3]) * scale);
      }
      #pragma unroll
      for (int kc = 0; kc < 4; ++kc)
        bQ[kc] = xpose(q01[2 * kc], q01[2 * kc + 1], q23[2 * kc], q23[2 * kc + 1], sa, sb, hi);
    }

    // S^T = mfma(K, Q); softmax; pack; transpose to aP
    bf16x8 aP[8];
    {
      f32x4 S[16];
      #pragma unroll
      for (int jt = 0; jt < 16; ++jt) S[jt] = Z4;
      #pragma unroll
      for (int kc = 0; kc < 4; ++kc) {
        #pragma unroll
        for (int jt = 0; jt < 16; ++jt) {
          bf16x8 bK = *(const bf16x8*)(Kb + (jt * 16 + lc) * 128 + (((kc * 4 + q4) ^ lc) << 3));
          S[jt] = MFMA(bK, bQ[kc], S[jt]);
        }
      }
      unsigned int p01[16], p23[16];
      softmax_pack(S, p01, p23);
      #pragma unroll
      for (int kc = 0; kc < 8; ++kc)
        aP[kc] = xpose(p01[2 * kc], p01[2 * kc + 1], p23[2 * kc], p23[2 * kc + 1], sa, sb, hi);
    }

    // Ct = mfma(V2^T, P): B-frags from the workspace slice (L2-hot)
    f32x4 Ct[8];
    #pragma unroll
    for (int nt = 0; nt < 8; ++nt) Ct[nt] = Z4;
    #pragma unroll
    for (int kc = 0; kc < 8; ++kc) {
      #pragma unroll
      for (int nt = 0; nt < 8; ++nt) {
        bf16x8 bV = *(const bf16x8*)(vsl + (nt * 16 + lc) * 256 + kc * 32 + q4 * 8);
        Ct[nt] = MFMA(bV, aP[kc], Ct[nt]);
      }
    }

    // V1^T projection from aE, then Ct *= (V1^T + bv1)
    {
      f32x4 Vt[8];
      #pragma unroll
      for (int nt = 0; nt < 8; ++nt) Vt[nt] = Z4;
      #pragma unroll
      for (int kc = 0; kc < 4; ++kc) {
        #pragma unroll
        for (int nt = 0; nt < 8; ++nt) {
          bf16x8 aW = *(const bf16x8*)(Wv1B + (nt * 16 + lc) * 128 + kc * 32 + q4 * 8);
          Vt[nt] = MFMA(aW, aE[kc], Vt[nt]);
        }
      }
      #pragma unroll
      for (int nt = 0; nt < 8; ++nt) {
        f32x4 b4 = *(const f32x4*)(bv1 + nt * 16 + q4 * 4);
        #pragma unroll
        for (int r = 0; r < 4; ++r) Ct[nt][r] *= (Vt[nt][r] + b4[r]);
      }
    }

    // transpose ctx to A-frags; O = ctx @ Wo^T + bo
    bf16x8 aC[4];
    {
      unsigned int c01[8], c23[8];
      #pragma unroll
      for (int nt = 0; nt < 8; ++nt) {
        c01[nt] = cvt_pk(Ct[nt][0], Ct[nt][1]);
        c23[nt] = cvt_pk(Ct[nt][2], Ct[nt][3]);
      }
      #pragma unroll
      for (int kc = 0; kc < 4; ++kc)
        aC[kc] = xpose(c01[2 * kc], c01[2 * kc + 1], c23[2 * kc], c23[2 * kc + 1], sa, sb, hi);
    }
    f32x4 O[8];
    #pragma unroll
    for (int n = 0; n < 8; ++n) O[n] = Z4;
    #pragma unroll
    for (int kc = 0; kc < 4; ++kc) {
      #pragma unroll
      for (int n = 0; n < 8; ++n) {
        bf16x8 bw = *(const bf16x8*)(WoB + (n * 16 + lc) * 128 + kc * 32 + q4 * 8);
        O[n] = MFMA(aC[kc], bw, O[n]);
      }
    }
    #pragma unroll
    for (int n = 0; n < 8; ++n) {
      const float bov = bo[n * 16 + lc];
      #pragma unroll
      for (int r = 0; r < 4; ++r) {
        const int i = i0 + q4 * 4 + r;
        out[(((size_t)(bb * 256 + i)) * 256 + lb) * 128 + n * 16 + lc] = O[n][r] + bov;
      }
    }
  }
}

// ---------------------------------------------------------------------------
// Fallback (ws too small): round-4 kernel verbatim (passed at 138 us).
// ---------------------------------------------------------------------------
__global__ __launch_bounds__(512, 2)
void edge_attn_r4(const float* __restrict__ ef,
                  const unsigned short* __restrict__ wbf,
                  const float* __restrict__ bq, const float* __restrict__ bk,
                  const float* __restrict__ bv1, const float* __restrict__ bv2,
                  const float* __restrict__ bo,
                  float* __restrict__ out) {
  __shared__ unsigned short Kb[256 * 128];
  __shared__ unsigned short V2t[128 * 256];

  const int tid  = threadIdx.x;
  const int lane = tid & 63;
  const int wv   = tid >> 6;
  const int lc   = lane & 15;
  const int q4   = lane >> 4;
  const int bb   = blockIdx.x >> 8;
  const int lb   = blockIdx.x & 255;

  const unsigned short* WqB  = wbf;
  const unsigned short* WkB  = wbf + 16384;
  const unsigned short* Wv1B = wbf + 2 * 16384;
  const unsigned short* Wv2B = wbf + 3 * 16384;
  const unsigned short* WoB  = wbf + 4 * 16384;

  const f32x4 Z4 = {0.f, 0.f, 0.f, 0.f};
  const int jA = wv * 16;
  const int jB = wv * 16 + 128;

  {
    const float* Frow = ef + ((size_t)(bb * 256 + lb)) * (256 * 128);
    bf16x8 aFA[4], aFB[4];
    {
      const float* rpA = Frow + (jA + lc) * 128 + q4 * 8;
      const float* rpB = Frow + (jB + lc) * 128 + q4 * 8;
      #pragma unroll
      for (int kc = 0; kc < 4; ++kc) {
        aFA[kc] = cvt_frag(rpA + kc * 32);
        aFB[kc] = cvt_frag(rpB + kc * 32);
      }
    }
    f32x4 aKA[8], aVA[8], aKB[8], aVB[8];
    #pragma unroll
    for (int n = 0; n < 8; ++n) { aKA[n] = Z4; aVA[n] = Z4; aKB[n] = Z4; aVB[n] = Z4; }
    #pragma unroll
    for (int kc = 0; kc < 4; ++kc) {
      #pragma unroll
      for (int n = 0; n < 8; ++n) {
        bf16x8 bwk = *(const bf16x8*)(WkB  + (n * 16 + lc) * 128 + kc * 32 + q4 * 8);
        bf16x8 bwv = *(const bf16x8*)(Wv2B + (n * 16 + lc) * 128 + kc * 32 + q4 * 8);
        aKA[n] = MFMA(aFA[kc], bwk, aKA[n]);
        aKB[n] = MFMA(aFB[kc], bwk, aKB[n]);
        aVA[n] = MFMA(aFA[kc], bwv, aVA[n]);
        aVB[n] = MFMA(aFB[kc], bwv, aVB[n]);
      }
    }
    #pragma unroll
    for (int n = 0; n < 8; ++n) {
      const int o = n * 16 + lc;
      const float bkv = bk[o];
      const float bvv = bv2[o];
      #pragma unroll
      for (int r = 0; r < 4; ++r) {
        const int ja = jA + q4 * 4 + r;
        const int jb = jB + q4 * 4 + r;
        Kb[ja * 128 + (((o >> 3) ^ (ja & 15)) << 3) + (o & 7)] = rne_bf16(aKA[n][r] + bkv);
        Kb[jb * 128 + (((o >> 3) ^ (jb & 15)) << 3) + (o & 7)] = rne_bf16(aKB[n][r] + bkv);
        V2t[o * 256 + (((ja >> 3) ^ lc) << 3) + (ja & 7)]      = rne_bf16(aVA[n][r] + bvv);
        V2t[o * 256 + (((jb >> 3) ^ lc) << 3) + (jb & 7)]      = rne_bf16(aVB[n][r] + bvv);
      }
    }
  }
  __syncthreads();

  const float scale = 0.08838834764831845f;
  bf16x8 aEA[4], aEB[4];
  {
    const float* rpA = ef + (((size_t)(bb * 256 + jA + lc)) * 256 + lb) * 128 + q4 * 8;
    const float* rpB = ef + (((size_t)(bb * 256 + jB + lc)) * 256 + lb) * 128 + q4 * 8;
    f32x4 eA[8], eB[8];
    #pragma unroll
    for (int kc = 0; kc < 4; ++kc) {
      eA[2 * kc]     = *(const f32x4*)(rpA + kc * 32);
      eA[2 * kc + 1] = *(const f32x4*)(rpA + kc * 32 + 4);
      eB[2 * kc]     = *(const f32x4*)(rpB + kc * 32);
      eB[2 * kc + 1] = *(const f32x4*)(rpB + kc * 32 + 4);
    }
    #pragma unroll
    for (int kc = 0; kc < 4; ++kc) {
      U8 u;
      u.w[0] = cvt_pk(eA[2 * kc][0], eA[2 * kc][1]);
      u.w[1] = cvt_pk(eA[2 * kc][2], eA[2 * kc][3]);
      u.w[2] = cvt_pk(eA[2 * kc + 1][0], eA[2 * kc + 1][1]);
      u.w[3] = cvt_pk(eA[2 * kc + 1][2], eA[2 * kc + 1][3]);
      aEA[kc] = u.v;
      u.w[0] = cvt_pk(eB[2 * kc][0], eB[2 * kc][1]);
      u.w[1] = cvt_pk(eB[2 * kc][2], eB[2 * kc][3]);
      u.w[2] = cvt_pk(eB[2 * kc + 1][0], eB[2 * kc + 1][1]);
      u.w[3] = cvt_pk(eB[2 * kc + 1][2], eB[2 * kc + 1][3]);
      aEB[kc] = u.v;
    }
  }

  f32x4 QtA[8], QtB[8];
  #pragma unroll
  for (int nt = 0; nt < 8; ++nt) { QtA[nt] = Z4; QtB[nt] = Z4; }
  #pragma unroll
  for (int kc = 0; kc < 4; ++kc) {
    #pragma unroll
    for (int nt = 0; nt < 8; ++nt) {
      bf16x8 aW = *(const bf16x8*)(WqB + (nt * 16 + lc) * 128 + kc * 32 + q4 * 8);
      QtA[nt] = MFMA(aW, aEA[kc], QtA[nt]);
      QtB[nt] = MFMA(aW, aEB[kc], QtB[nt]);
    }
  }
  unsigned int qA01[8], qA23[8], qB01[8], qB23[8];
  #pragma unroll
  for (int nt = 0; nt < 8; ++nt) {
    f32x4 b4 = *(const f32x4*)(bq + nt * 16 + q4 * 4);
    qA01[nt] = cvt_pk((QtA[nt][0] + b4[0]) * scale, (QtA[nt][1] + b4[1]) * scale);
    qA23[nt] = cvt_pk((QtA[nt][2] + b4[2]) * scale, (QtA[nt][3] + b4[3]) * scale);
    qB01[nt] = cvt_pk((QtB[nt][0] + b4[0]) * scale, (QtB[nt][1] + b4[1]) * scale);
    qB23[nt] = cvt_pk((QtB[nt][2] + b4[2]) * scale, (QtB[nt][3] + b4[3]) * scale);
  }

  const int sa = ((2 * q4) & 3) * 16 + lc;
  const int sb = ((2 * q4 + 1) & 3) * 16 + lc;
  const bool hi = (q4 >= 2);

  bf16x8 bQA[4], bQB[4];
  #pragma unroll
  for (int kc = 0; kc < 4; ++kc) {
    bQA[kc] = xpose(qA01[2 * kc], qA01[2 * kc + 1], qA23[2 * kc], qA23[2 * kc + 1], sa, sb, hi);
    bQB[kc] = xpose(qB01[2 * kc], qB01[2 * kc + 1], qB23[2 * kc], qB23[2 * kc + 1], sa, sb, hi);
  }

  f32x4 SA[16], SB[16];
  #pragma unroll
  for (int jt = 0; jt < 16; ++jt) { SA[jt] = Z4; SB[jt] = Z4; }
  #pragma unroll
  for (int kc = 0; kc < 4; ++kc) {
    #pragma unroll
    for (int jt = 0; jt < 16; ++jt) {
      bf16x8 bK = *(const bf16x8*)(Kb + (jt * 16 + lc) * 128 + (((kc * 4 + q4) ^ lc) << 3));
      SA[jt] = MFMA(bK, bQA[kc], SA[jt]);
      SB[jt] = MFMA(bK, bQB[kc], SB[jt]);
    }
  }

  unsigned int pA01[16], pA23[16], pB01[16], pB23[16];
  softmax_pack(SA, pA01, pA23);
  softmax_pack(SB, pB01, pB23);

  bf16x8 aPA[8], aPB[8];
  #pragma unroll
  for (int kc = 0; kc < 8; ++kc) {
    aPA[kc] = xpose(pA01[2 * kc], pA01[2 * kc + 1], pA23[2 * kc], pA23[2 * kc + 1], sa, sb, hi);
    aPB[kc] = xpose(pB01[2 * kc], pB01[2 * kc + 1], pB23[2 * kc], pB23[2 * kc + 1], sa, sb, hi);
  }

  f32x4 CA[8], CB[8];
  #pragma unroll
  for (int nt = 0; nt < 8; ++nt) { CA[nt] = Z4; CB[nt] = Z4; }
  #pragma unroll
  for (int kc = 0; kc < 8; ++kc) {
    #pragma unroll
    for (int nt = 0; nt < 8; ++nt) {
      bf16x8 bV = *(const bf16x8*)(V2t + (nt * 16 + lc) * 256 + (((kc * 4 + q4) ^ lc) << 3));
      CA[nt] = MFMA(bV, aPA[kc], CA[nt]);
      CB[nt] = MFMA(bV, aPB[kc], CB[nt]);
    }
  }

  f32x4 VA[8], VB[8];
  #pragma unroll
  for (int nt = 0; nt < 8; ++nt) { VA[nt] = Z4; VB[nt] = Z4; }
  #pragma unroll
  for (int kc = 0; kc < 4; ++kc) {
    #pragma unroll
    for (int nt = 0; nt < 8; ++nt) {
      bf16x8 aW = *(const bf16x8*)(Wv1B + (nt * 16 + lc) * 128 + kc * 32 + q4 * 8);
      VA[nt] = MFMA(aW, aEA[kc], VA[nt]);
      VB[nt] = MFMA(aW, aEB[kc], VB[nt]);
    }
  }
  #pragma unroll
  for (int nt = 0; nt < 8; ++nt) {
    f32x4 b4 = *(const f32x4*)(bv1 + nt * 16 + q4 * 4);
    #pragma unroll
    for (int r = 0; r < 4; ++r) {
      CA[nt][r] *= (VA[nt][r] + b4[r]);
      CB[nt][r] *= (VB[nt][r] + b4[r]);
    }
  }

  unsigned int cA01[8], cA23[8], cB01[8], cB23[8];
  #pragma unroll
  for (int nt = 0; nt < 8; ++nt) {
    cA01[nt] = cvt_pk(CA[nt][0], CA[nt][1]);
    cA23[nt] = cvt_pk(CA[nt][2], CA[nt][3]);
    cB01[nt] = cvt_pk(CB[nt][0], CB[nt][1]);
    cB23[nt] = cvt_pk(CB[nt][2], CB[nt][3]);
  }
  bf16x8 aCA[4], aCB[4];
  #pragma unroll
  for (int kc = 0; kc < 4; ++kc) {
    aCA[kc] = xpose(cA01[2 * kc], cA01[2 * kc + 1], cA23[2 * kc], cA23[2 * kc + 1], sa, sb, hi);
    aCB[kc] = xpose(cB01[2 * kc], cB01[2 * kc + 1], cB23[2 * kc], cB23[2 * kc + 1], sa, sb, hi);
  }

  f32x4 OA[8], OB[8];
  #pragma unroll
  for (int n = 0; n < 8; ++n) { OA[n] = Z4; OB[n] = Z4; }
  #pragma unroll
  for (int kc = 0; kc < 4; ++kc) {
    #pragma unroll
    for (int n = 0; n < 8; ++n) {
      bf16x8 bw = *(const bf16x8*)(WoB + (n * 16 + lc) * 128 + kc * 32 + q4 * 8);
      OA[n] = MFMA(aCA[kc], bw, OA[n]);
      OB[n] = MFMA(aCB[kc], bw, OB[n]);
    }
  }
  #pragma unroll
  for (int n = 0; n < 8; ++n) {
    const float bov = bo[n * 16 + lc];
    #pragma unroll
    for (int r = 0; r < 4; ++r) {
      const int ia = jA + q4 * 4 + r;
      const int ib = jB + q4 * 4 + r;
      out[(((size_t)(bb * 256 + ia)) * 256 + lb) * 128 + n * 16 + lc] = OA[n][r] + bov;
      out[(((size_t)(bb * 256 + ib)) * 256 + lb) * 128 + n * 16 + lc] = OB[n][r] + bov;
    }
  }
}

extern "C" void kernel_launch(void* const* d_in, const int* in_sizes, int n_in,
                              void* d_out, int out_size, void* d_ws, size_t ws_size,
                              hipStream_t stream) {
  const float* ef   = (const float*)d_in[0];
  const float* Wq   = (const float*)d_in[1];
  const float* bqp  = (const float*)d_in[2];
  const float* Wk   = (const float*)d_in[3];
  const float* bkp  = (const float*)d_in[4];
  const float* Wv1  = (const float*)d_in[5];
  const float* bv1p = (const float*)d_in[6];
  const float* Wv2  = (const float*)d_in[7];
  const float* bv2p = (const float*)d_in[8];
  const float* Wo   = (const float*)d_in[9];
  const float* bop  = (const float*)d_in[10];
  unsigned short* wbf = (unsigned short*)d_ws;

  cvt_weights<<<64, 256, 0, stream>>>(Wq, Wk, Wv1, Wv2, Wo, wbf);

  if (ws_size >= WS_NEEDED) {
    edge_attn_kernel<<<512, 512, 0, stream>>>(ef, wbf, bqp, bkp, bv1p, bv2p, bop,
                                              (float*)d_out);
  } else {
    edge_attn_r4<<<512, 512, 0, stream>>>(ef, wbf, bqp, bkp, bv1p, bv2p, bop,
                                          (float*)d_out);
  }
}

// Round 6
// 195.783 us; speedup vs baseline: 2.5021x; 2.5021x over previous
//
#include <hip/hip_runtime.h>

// EdgeAttention fused kernel for MI355X (gfx950) — round 6.
// Base = round-4 structure (512 thr = 8 waves, 2-deep A/B tile lockstep,
// launch_bounds(512,2), shuffle transposes, lane-local softmax). New: the four
// projection weight matrices Wk/Wq/Wv1/Wo are staged through a 32 KB rotating
// LDS buffer (Kb-style XOR swizzle; coalesced 64B/thread staging loads issued
// just before a __syncthreads so the barrier's vmcnt drain absorbs their
// latency). Per-wave global loads drop 192 -> ~86. Wv2 remains global (no
// spare LDS during the fused phase-1 pass). Numerics identical to round 4.
// LDS = Kb 64K + V2t 64K + Wl 32K = 160 KB exactly; hipGetLastError fallback
// to the round-4 kernel guards the 160 KB launch.
// MFMA layouts (m89/m91/m120-verified):
//   A/B-frag: elem[j] = X[row = lane&15][k = (lane>>4)*8 + j]
//   C/D     : c[r] = D[m = (lane>>4)*4 + r][n = lane&15]

typedef __bf16 bf16x8 __attribute__((ext_vector_type(8)));
typedef float  f32x4  __attribute__((ext_vector_type(4)));
typedef unsigned short u16x4 __attribute__((ext_vector_type(4)));

#define MFMA(a, b, c) __builtin_amdgcn_mfma_f32_16x16x32_bf16((a), (b), (c), 0, 0, 0)

union U8 { bf16x8 v; unsigned int w[4]; };

__device__ __forceinline__ unsigned short rne_bf16(float f) {
  unsigned int u = __float_as_uint(f);
  u += 0x7fffu + ((u >> 16) & 1u);   // round-to-nearest-even
  return (unsigned short)(u >> 16);
}

__device__ __forceinline__ unsigned int cvt_pk(float lo, float hi) {
  unsigned int r;
  asm("v_cvt_pk_bf16_f32 %0, %1, %2" : "=v"(r) : "v"(lo), "v"(hi));
  return r;
}

__device__ __forceinline__ bf16x8 cvt_frag(const float* __restrict__ p) {
  f32x4 a = *(const f32x4*)p;
  f32x4 b = *(const f32x4*)(p + 4);
  U8 t;
  t.w[0] = cvt_pk(a[0], a[1]);
  t.w[1] = cvt_pk(a[2], a[3]);
  t.w[2] = cvt_pk(b[0], b[1]);
  t.w[3] = cvt_pk(b[2], b[3]);
  return t.v;
}

// cross-q4 transpose (round-3 verified): C-layout packed pairs -> A/B-frag.
__device__ __forceinline__ bf16x8 xpose(unsigned int w01a, unsigned int w01b,
                                        unsigned int w23a, unsigned int w23b,
                                        int sa, int sb, bool hi) {
  U8 u;
  { int x0 = __shfl((int)w01a, sa), x1 = __shfl((int)w01b, sa);
    u.w[0] = (unsigned int)(hi ? x1 : x0); }
  { int x0 = __shfl((int)w23a, sa), x1 = __shfl((int)w23b, sa);
    u.w[1] = (unsigned int)(hi ? x1 : x0); }
  { int x0 = __shfl((int)w01a, sb), x1 = __shfl((int)w01b, sb);
    u.w[2] = (unsigned int)(hi ? x1 : x0); }
  { int x0 = __shfl((int)w23a, sb), x1 = __shfl((int)w23b, sb);
    u.w[3] = (unsigned int)(hi ? x1 : x0); }
  return u.v;
}

// lane-local softmax over j (round-3 verified).
__device__ __forceinline__ void softmax_pack(f32x4 ST[16], unsigned int p01[16],
                                             unsigned int p23[16]) {
  float t16[16];
  #pragma unroll
  for (int jt = 0; jt < 16; ++jt)
    t16[jt] = fmaxf(fmaxf(ST[jt][0], ST[jt][1]), fmaxf(ST[jt][2], ST[jt][3]));
  #pragma unroll
  for (int s = 8; s >= 1; s >>= 1)
    #pragma unroll
    for (int k = 0; k < 16; ++k) if (k < s) t16[k] = fmaxf(t16[k], t16[k + s]);
  float mx = t16[0];
  mx = fmaxf(mx, __shfl_xor(mx, 16));
  mx = fmaxf(mx, __shfl_xor(mx, 32));

  float s16[16];
  #pragma unroll
  for (int jt = 0; jt < 16; ++jt) {
    float e0 = __expf(ST[jt][0] - mx);
    float e1 = __expf(ST[jt][1] - mx);
    float e2 = __expf(ST[jt][2] - mx);
    float e3 = __expf(ST[jt][3] - mx);
    ST[jt][0] = e0; ST[jt][1] = e1; ST[jt][2] = e2; ST[jt][3] = e3;
    s16[jt] = (e0 + e1) + (e2 + e3);
  }
  #pragma unroll
  for (int s = 8; s >= 1; s >>= 1)
    #pragma unroll
    for (int k = 0; k < 16; ++k) if (k < s) s16[k] += s16[k + s];
  float sm = s16[0];
  sm += __shfl_xor(sm, 16);
  sm += __shfl_xor(sm, 32);
  const float inv = 1.0f / sm;

  #pragma unroll
  for (int jt = 0; jt < 16; ++jt) {
    p01[jt] = cvt_pk(ST[jt][0] * inv, ST[jt][1] * inv);
    p23[jt] = cvt_pk(ST[jt][2] * inv, ST[jt][3] * inv);
  }
}

// --- weight staging: Wl holds one 128x128 bf16 matrix, Kb-style swizzle ------
// layout: elem (o,e) at o*128 + (((e>>3) ^ (o&15))<<3) + (e&7)
// stage_load: 64 B/thread, globally COALESCED (linear slots); stage_write puts
// each 16 B chunk at its swizzled slot. Verified mapping: LDS slot s of row o
// holds global elements e/8 = s ^ (o&15).
__device__ __forceinline__ void stage_load(const unsigned short* __restrict__ src,
                                           int tid, f32x4 b[4]) {
  const int o   = tid >> 2;
  const int S0  = (tid & 3) * 4;
  const int m12 = (o & 15) & 12;
  const float* s = (const float*)(src + o * 128 + ((S0 ^ m12) << 3));
  #pragma unroll
  for (int q = 0; q < 4; ++q) b[q] = *(const f32x4*)(s + q * 4);
}
__device__ __forceinline__ void stage_write(unsigned short* __restrict__ Wl,
                                            int tid, const f32x4 b[4]) {
  const int o  = tid >> 2;
  const int S0 = (tid & 3) * 4;
  const int p  = o & 3;
  #pragma unroll
  for (int q = 0; q < 4; ++q)
    *(f32x4*)(Wl + o * 128 + ((S0 + (q ^ p)) << 3)) = b[q];
}

// Setup: convert the 5 weight matrices fp32 -> bf16 into d_ws.
__global__ void cvt_weights(const float* __restrict__ Wq, const float* __restrict__ Wk,
                            const float* __restrict__ Wv1, const float* __restrict__ Wv2,
                            const float* __restrict__ Wo, unsigned short* __restrict__ ws) {
  int t = blockIdx.x * 256 + threadIdx.x;   // 0..16383
  ws[t]             = rne_bf16(Wq[t]);
  ws[16384 + t]     = rne_bf16(Wk[t]);
  ws[2 * 16384 + t] = rne_bf16(Wv1[t]);
  ws[3 * 16384 + t] = rne_bf16(Wv2[t]);
  ws[4 * 16384 + t] = rne_bf16(Wo[t]);
}

// ---------------------------------------------------------------------------
// Round-6 kernel: R4 + LDS-staged weights (160 KB LDS).
// ---------------------------------------------------------------------------
__global__ __launch_bounds__(512, 2)
void edge_attn_v6(const float* __restrict__ ef,
                  const unsigned short* __restrict__ wbf,
                  const float* __restrict__ bq, const float* __restrict__ bk,
                  const float* __restrict__ bv1, const float* __restrict__ bv2,
                  const float* __restrict__ bo,
                  float* __restrict__ out) {
  __shared__ unsigned short Kb[256 * 128];   // 64 KB, (j,o) swizzled
  __shared__ unsigned short V2t[128 * 256];  // 64 KB, (d,j) swizzled
  __shared__ unsigned short Wl[128 * 128];   // 32 KB rotating weight buffer

  const int tid  = threadIdx.x;
  const int lane = tid & 63;
  const int wv   = tid >> 6;    // wave 0..7
  const int lc   = lane & 15;
  const int q4   = lane >> 4;
  const int bb   = blockIdx.x >> 8;
  const int lb   = blockIdx.x & 255;

  const unsigned short* WqB  = wbf;
  const unsigned short* WkB  = wbf + 16384;
  const unsigned short* Wv1B = wbf + 2 * 16384;
  const unsigned short* Wv2B = wbf + 3 * 16384;
  const unsigned short* WoB  = wbf + 4 * 16384;

  const f32x4 Z4 = {0.f, 0.f, 0.f, 0.f};
  const int jA = wv * 16;         // tile A rows (phase1 j / phase2 i)
  const int jB = wv * 16 + 128;   // tile B rows

  // swizzled weight-fragment read from Wl (2-way bank aliasing = free)
  #define WFRAG(nt, kc) \
    (*(const bf16x8*)(Wl + ((nt) * 16 + lc) * 128 + ((((kc) * 4 + q4) ^ lc) << 3)))

  f32x4 sbuf[4];   // staging registers

  // ---------------- Phase 1: K -> Kb (Wk from LDS), V2 -> V2t (Wv2 global) --
  stage_load(WkB, tid, sbuf);

  bf16x8 aFA[4], aFB[4];
  {
    const float* Frow = ef + ((size_t)(bb * 256 + lb)) * (256 * 128);
    const float* rpA = Frow + (jA + lc) * 128 + q4 * 8;
    const float* rpB = Frow + (jB + lc) * 128 + q4 * 8;
    #pragma unroll
    for (int kc = 0; kc < 4; ++kc) {
      aFA[kc] = cvt_frag(rpA + kc * 32);
      aFB[kc] = cvt_frag(rpB + kc * 32);
    }
  }
  stage_write(Wl, tid, sbuf);
  __syncthreads();                 // Wk visible

  {
    f32x4 aKA[8], aVA[8], aKB[8], aVB[8];
    #pragma unroll
    for (int n = 0; n < 8; ++n) { aKA[n] = Z4; aVA[n] = Z4; aKB[n] = Z4; aVB[n] = Z4; }
    #pragma unroll
    for (int kc = 0; kc < 4; ++kc) {
      #pragma unroll
      for (int n = 0; n < 8; ++n) {
        bf16x8 bwk = WFRAG(n, kc);
        bf16x8 bwv = *(const bf16x8*)(Wv2B + (n * 16 + lc) * 128 + kc * 32 + q4 * 8);
        aKA[n] = MFMA(aFA[kc], bwk, aKA[n]);
        aKB[n] = MFMA(aFB[kc], bwk, aKB[n]);
        aVA[n] = MFMA(aFA[kc], bwv, aVA[n]);
        aVB[n] = MFMA(aFB[kc], bwv, aVB[n]);
      }
    }
    #pragma unroll
    for (int n = 0; n < 8; ++n) {
      const int o = n * 16 + lc;
      const float bkv = bk[o];
      const float bvv = bv2[o];
      u16x4 pkA, pkB;
      #pragma unroll
      for (int r = 0; r < 4; ++r) {
        const int ja = jA + q4 * 4 + r;
        const int jb = jB + q4 * 4 + r;
        Kb[ja * 128 + (((o >> 3) ^ (ja & 15)) << 3) + (o & 7)] = rne_bf16(aKA[n][r] + bkv);
        Kb[jb * 128 + (((o >> 3) ^ (jb & 15)) << 3) + (o & 7)] = rne_bf16(aKB[n][r] + bkv);
        pkA[r] = rne_bf16(aVA[n][r] + bvv);
        pkB[r] = rne_bf16(aVB[n][r] + bvv);
      }
      // V2t (d,j): j&7 = (q4&1)*4 + r is r-contiguous -> 8B store
      const int sgA = (wv * 2 + (q4 >> 1)) ^ (o & 15);
      const int sgB = (16 + wv * 2 + (q4 >> 1)) ^ (o & 15);
      *(u16x4*)(V2t + o * 256 + (sgA << 3) + (q4 & 1) * 4) = pkA;
      *(u16x4*)(V2t + o * 256 + (sgB << 3) + (q4 & 1) * 4) = pkB;
    }
  }

  // issue next-stage loads + phase-2 E i-rows before the barrier (drain hides them)
  stage_load(WqB, tid, sbuf);
  f32x4 eA[8], eB[8];
  {
    const float* rpA = ef + (((size_t)(bb * 256 + jA + lc)) * 256 + lb) * 128 + q4 * 8;
    const float* rpB = ef + (((size_t)(bb * 256 + jB + lc)) * 256 + lb) * 128 + q4 * 8;
    #pragma unroll
    for (int kc = 0; kc < 4; ++kc) {
      eA[2 * kc]     = *(const f32x4*)(rpA + kc * 32);
      eA[2 * kc + 1] = *(const f32x4*)(rpA + kc * 32 + 4);
      eB[2 * kc]     = *(const f32x4*)(rpB + kc * 32);
      eB[2 * kc + 1] = *(const f32x4*)(rpB + kc * 32 + 4);
    }
  }
  __syncthreads();                 // all waves done reading Wk; loads drained
  stage_write(Wl, tid, sbuf);
  __syncthreads();                 // Wq visible

  // ---------------- Phase 2: two i-tiles per wave, lockstep -----------------
  const float scale = 0.08838834764831845f;  // 1/sqrt(128)

  bf16x8 aEA[4], aEB[4];
  #pragma unroll
  for (int kc = 0; kc < 4; ++kc) {
    U8 u;
    u.w[0] = cvt_pk(eA[2 * kc][0], eA[2 * kc][1]);
    u.w[1] = cvt_pk(eA[2 * kc][2], eA[2 * kc][3]);
    u.w[2] = cvt_pk(eA[2 * kc + 1][0], eA[2 * kc + 1][1]);
    u.w[3] = cvt_pk(eA[2 * kc + 1][2], eA[2 * kc + 1][3]);
    aEA[kc] = u.v;
    u.w[0] = cvt_pk(eB[2 * kc][0], eB[2 * kc][1]);
    u.w[1] = cvt_pk(eB[2 * kc][2], eB[2 * kc][3]);
    u.w[2] = cvt_pk(eB[2 * kc + 1][0], eB[2 * kc + 1][1]);
    u.w[3] = cvt_pk(eB[2 * kc + 1][2], eB[2 * kc + 1][3]);
    aEB[kc] = u.v;
  }

  // Q^T projection (Wq from LDS)
  f32x4 QtA[8], QtB[8];
  #pragma unroll
  for (int nt = 0; nt < 8; ++nt) { QtA[nt] = Z4; QtB[nt] = Z4; }
  #pragma unroll
  for (int kc = 0; kc < 4; ++kc) {
    #pragma unroll
    for (int nt = 0; nt < 8; ++nt) {
      bf16x8 aW = WFRAG(nt, kc);
      QtA[nt] = MFMA(aW, aEA[kc], QtA[nt]);
      QtB[nt] = MFMA(aW, aEB[kc], QtB[nt]);
    }
  }
  unsigned int qA01[8], qA23[8], qB01[8], qB23[8];
  #pragma unroll
  for (int nt = 0; nt < 8; ++nt) {
    f32x4 b4 = *(const f32x4*)(bq + nt * 16 + q4 * 4);
    qA01[nt] = cvt_pk((QtA[nt][0] + b4[0]) * scale, (QtA[nt][1] + b4[1]) * scale);
    qA23[nt] = cvt_pk((QtA[nt][2] + b4[2]) * scale, (QtA[nt][3] + b4[3]) * scale);
    qB01[nt] = cvt_pk((QtB[nt][0] + b4[0]) * scale, (QtB[nt][1] + b4[1]) * scale);
    qB23[nt] = cvt_pk((QtB[nt][2] + b4[2]) * scale, (QtB[nt][3] + b4[3]) * scale);
  }

  const int sa = ((2 * q4) & 3) * 16 + lc;
  const int sb = ((2 * q4 + 1) & 3) * 16 + lc;
  const bool hi = (q4 >= 2);

  bf16x8 bQA[4], bQB[4];
  #pragma unroll
  for (int kc = 0; kc < 4; ++kc) {
    bQA[kc] = xpose(qA01[2 * kc], qA01[2 * kc + 1], qA23[2 * kc], qA23[2 * kc + 1], sa, sb, hi);
    bQB[kc] = xpose(qB01[2 * kc], qB01[2 * kc + 1], qB23[2 * kc], qB23[2 * kc + 1], sa, sb, hi);
  }

  // S^T = mfma(K, Q) — K frags shared A/B
  f32x4 SA[16], SB[16];
  #pragma unroll
  for (int jt = 0; jt < 16; ++jt) { SA[jt] = Z4; SB[jt] = Z4; }
  #pragma unroll
  for (int kc = 0; kc < 4; ++kc) {
    #pragma unroll
    for (int jt = 0; jt < 16; ++jt) {
      bf16x8 bK = *(const bf16x8*)(Kb + (jt * 16 + lc) * 128 + (((kc * 4 + q4) ^ lc) << 3));
      SA[jt] = MFMA(bK, bQA[kc], SA[jt]);
      SB[jt] = MFMA(bK, bQB[kc], SB[jt]);
    }
  }

  unsigned int pA01[16], pA23[16], pB01[16], pB23[16];
  softmax_pack(SA, pA01, pA23);
  softmax_pack(SB, pB01, pB23);

  stage_load(Wv1B, tid, sbuf);     // issue; drained by the next barrier
  __syncthreads();                 // all waves done reading Wq
  stage_write(Wl, tid, sbuf);
  __syncthreads();                 // Wv1 visible

  bf16x8 aPA[8], aPB[8];
  #pragma unroll
  for (int kc = 0; kc < 8; ++kc) {
    aPA[kc] = xpose(pA01[2 * kc], pA01[2 * kc + 1], pA23[2 * kc], pA23[2 * kc + 1], sa, sb, hi);
    aPB[kc] = xpose(pB01[2 * kc], pB01[2 * kc + 1], pB23[2 * kc], pB23[2 * kc + 1], sa, sb, hi);
  }

  // Ct = mfma(V2^T, P) — V2 frags shared A/B
  f32x4 CA[8], CB[8];
  #pragma unroll
  for (int nt = 0; nt < 8; ++nt) { CA[nt] = Z4; CB[nt] = Z4; }
  #pragma unroll
  for (int kc = 0; kc < 8; ++kc) {
    #pragma unroll
    for (int nt = 0; nt < 8; ++nt) {
      bf16x8 bV = *(const bf16x8*)(V2t + (nt * 16 + lc) * 256 + (((kc * 4 + q4) ^ lc) << 3));
      CA[nt] = MFMA(bV, aPA[kc], CA[nt]);
      CB[nt] = MFMA(bV, aPB[kc], CB[nt]);
    }
  }

  // V1^T projection (Wv1 from LDS), then Ct *= (V1^T + bv1)
  {
    f32x4 VA[8], VB[8];
    #pragma unroll
    for (int nt = 0; nt < 8; ++nt) { VA[nt] = Z4; VB[nt] = Z4; }
    #pragma unroll
    for (int kc = 0; kc < 4; ++kc) {
      #pragma unroll
      for (int nt = 0; nt < 8; ++nt) {
        bf16x8 aW = WFRAG(nt, kc);
        VA[nt] = MFMA(aW, aEA[kc], VA[nt]);
        VB[nt] = MFMA(aW, aEB[kc], VB[nt]);
      }
    }
    #pragma unroll
    for (int nt = 0; nt < 8; ++nt) {
      f32x4 b4 = *(const f32x4*)(bv1 + nt * 16 + q4 * 4);
      #pragma unroll
      for (int r = 0; r < 4; ++r) {
        CA[nt][r] *= (VA[nt][r] + b4[r]);
        CB[nt][r] *= (VB[nt][r] + b4[r]);
      }
    }
  }

  stage_load(WoB, tid, sbuf);      // issue; drained by the next barrier
  __syncthreads();                 // all waves done reading Wv1
  stage_write(Wl, tid, sbuf);
  __syncthreads();                 // Wo visible

  unsigned int cA01[8], cA23[8], cB01[8], cB23[8];
  #pragma unroll
  for (int nt = 0; nt < 8; ++nt) {
    cA01[nt] = cvt_pk(CA[nt][0], CA[nt][1]);
    cA23[nt] = cvt_pk(CA[nt][2], CA[nt][3]);
    cB01[nt] = cvt_pk(CB[nt][0], CB[nt][1]);
    cB23[nt] = cvt_pk(CB[nt][2], CB[nt][3]);
  }
  bf16x8 aCA[4], aCB[4];
  #pragma unroll
  for (int kc = 0; kc < 4; ++kc) {
    aCA[kc] = xpose(cA01[2 * kc], cA01[2 * kc + 1], cA23[2 * kc], cA23[2 * kc + 1], sa, sb, hi);
    aCB[kc] = xpose(cB01[2 * kc], cB01[2 * kc + 1], cB23[2 * kc], cB23[2 * kc + 1], sa, sb, hi);
  }

  // O = ctx @ Wo^T + bo (Wo from LDS; C-layout, coalesced store)
  f32x4 OA[8], OB[8];
  #pragma unroll
  for (int n = 0; n < 8; ++n) { OA[n] = Z4; OB[n] = Z4; }
  #pragma unroll
  for (int kc = 0; kc < 4; ++kc) {
    #pragma unroll
    for (int n = 0; n < 8; ++n) {
      bf16x8 bw = WFRAG(n, kc);
      OA[n] = MFMA(aCA[kc], bw, OA[n]);
      OB[n] = MFMA(aCB[kc], bw, OB[n]);
    }
  }
  #pragma unroll
  for (int n = 0; n < 8; ++n) {
    const float bov = bo[n * 16 + lc];
    #pragma unroll
    for (int r = 0; r < 4; ++r) {
      const int ia = jA + q4 * 4 + r;
      const int ib = jB + q4 * 4 + r;
      out[(((size_t)(bb * 256 + ia)) * 256 + lb) * 128 + n * 16 + lc] = OA[n][r] + bov;
      out[(((size_t)(bb * 256 + ib)) * 256 + lb) * 128 + n * 16 + lc] = OB[n][r] + bov;
    }
  }
  #undef WFRAG
}

// ---------------------------------------------------------------------------
// Fallback: round-4 kernel verbatim (138 us kernel), used if 160 KB LDS
// launch fails.
// ---------------------------------------------------------------------------
__global__ __launch_bounds__(512, 2)
void edge_attn_r4(const float* __restrict__ ef,
                  const unsigned short* __restrict__ wbf,
                  const float* __restrict__ bq, const float* __restrict__ bk,
                  const float* __restrict__ bv1, const float* __restrict__ bv2,
                  const float* __restrict__ bo,
                  float* __restrict__ out) {
  __shared__ unsigned short Kb[256 * 128];
  __shared__ unsigned short V2t[128 * 256];

  const int tid  = threadIdx.x;
  const int lane = tid & 63;
  const int wv   = tid >> 6;
  const int lc   = lane & 15;
  const int q4   = lane >> 4;
  const int bb   = blockIdx.x >> 8;
  const int lb   = blockIdx.x & 255;

  const unsigned short* WqB  = wbf;
  const unsigned short* WkB  = wbf + 16384;
  const unsigned short* Wv1B = wbf + 2 * 16384;
  const unsigned short* Wv2B = wbf + 3 * 16384;
  const unsigned short* WoB  = wbf + 4 * 16384;

  const f32x4 Z4 = {0.f, 0.f, 0.f, 0.f};
  const int jA = wv * 16;
  const int jB = wv * 16 + 128;

  {
    const float* Frow = ef + ((size_t)(bb * 256 + lb)) * (256 * 128);
    bf16x8 aFA[4], aFB[4];
    {
      const float* rpA = Frow + (jA + lc) * 128 + q4 * 8;
      const float* rpB = Frow + (jB + lc) * 128 + q4 * 8;
      #pragma unroll
      for (int kc = 0; kc < 4; ++kc) {
        aFA[kc] = cvt_frag(rpA + kc * 32);
        aFB[kc] = cvt_frag(rpB + kc * 32);
      }
    }
    f32x4 aKA[8], aVA[8], aKB[8], aVB[8];
    #pragma unroll
    for (int n = 0; n < 8; ++n) { aKA[n] = Z4; aVA[n] = Z4; aKB[n] = Z4; aVB[n] = Z4; }
    #pragma unroll
    for (int kc = 0; kc < 4; ++kc) {
      #pragma unroll
      for (int n = 0; n < 8; ++n) {
        bf16x8 bwk = *(const bf16x8*)(WkB  + (n * 16 + lc) * 128 + kc * 32 + q4 * 8);
        bf16x8 bwv = *(const bf16x8*)(Wv2B + (n * 16 + lc) * 128 + kc * 32 + q4 * 8);
        aKA[n] = MFMA(aFA[kc], bwk, aKA[n]);
        aKB[n] = MFMA(aFB[kc], bwk, aKB[n]);
        aVA[n] = MFMA(aFA[kc], bwv, aVA[n]);
        aVB[n] = MFMA(aFB[kc], bwv, aVB[n]);
      }
    }
    #pragma unroll
    for (int n = 0; n < 8; ++n) {
      const int o = n * 16 + lc;
      const float bkv = bk[o];
      const float bvv = bv2[o];
      #pragma unroll
      for (int r = 0; r < 4; ++r) {
        const int ja = jA + q4 * 4 + r;
        const int jb = jB + q4 * 4 + r;
        Kb[ja * 128 + (((o >> 3) ^ (ja & 15)) << 3) + (o & 7)] = rne_bf16(aKA[n][r] + bkv);
        Kb[jb * 128 + (((o >> 3) ^ (jb & 15)) << 3) + (o & 7)] = rne_bf16(aKB[n][r] + bkv);
        V2t[o * 256 + (((ja >> 3) ^ lc) << 3) + (ja & 7)]      = rne_bf16(aVA[n][r] + bvv);
        V2t[o * 256 + (((jb >> 3) ^ lc) << 3) + (jb & 7)]      = rne_bf16(aVB[n][r] + bvv);
      }
    }
  }
  __syncthreads();

  const float scale = 0.08838834764831845f;
  bf16x8 aEA[4], aEB[4];
  {
    const float* rpA = ef + (((size_t)(bb * 256 + jA + lc)) * 256 + lb) * 128 + q4 * 8;
    const float* rpB = ef + (((size_t)(bb * 256 + jB + lc)) * 256 + lb) * 128 + q4 * 8;
    f32x4 eA[8], eB[8];
    #pragma unroll
    for (int kc = 0; kc < 4; ++kc) {
      eA[2 * kc]     = *(const f32x4*)(rpA + kc * 32);
      eA[2 * kc + 1] = *(const f32x4*)(rpA + kc * 32 + 4);
      eB[2 * kc]     = *(const f32x4*)(rpB + kc * 32);
      eB[2 * kc + 1] = *(const f32x4*)(rpB + kc * 32 + 4);
    }
    #pragma unroll
    for (int kc = 0; kc < 4; ++kc) {
      U8 u;
      u.w[0] = cvt_pk(eA[2 * kc][0], eA[2 * kc][1]);
      u.w[1] = cvt_pk(eA[2 * kc][2], eA[2 * kc][3]);
      u.w[2] = cvt_pk(eA[2 * kc + 1][0], eA[2 * kc + 1][1]);
      u.w[3] = cvt_pk(eA[2 * kc + 1][2], eA[2 * kc + 1][3]);
      aEA[kc] = u.v;
      u.w[0] = cvt_pk(eB[2 * kc][0], eB[2 * kc][1]);
      u.w[1] = cvt_pk(eB[2 * kc][2], eB[2 * kc][3]);
      u.w[2] = cvt_pk(eB[2 * kc + 1][0], eB[2 * kc + 1][1]);
      u.w[3] = cvt_pk(eB[2 * kc + 1][2], eB[2 * kc + 1][3]);
      aEB[kc] = u.v;
    }
  }

  f32x4 QtA[8], QtB[8];
  #pragma unroll
  for (int nt = 0; nt < 8; ++nt) { QtA[nt] = Z4; QtB[nt] = Z4; }
  #pragma unroll
  for (int kc = 0; kc < 4; ++kc) {
    #pragma unroll
    for (int nt = 0; nt < 8; ++nt) {
      bf16x8 aW = *(const bf16x8*)(WqB + (nt * 16 + lc) * 128 + kc * 32 + q4 * 8);
      QtA[nt] = MFMA(aW, aEA[kc], QtA[nt]);
      QtB[nt] = MFMA(aW, aEB[kc], QtB[nt]);
    }
  }
  unsigned int qA01[8], qA23[8], qB01[8], qB23[8];
  #pragma unroll
  for (int nt = 0; nt < 8; ++nt) {
    f32x4 b4 = *(const f32x4*)(bq + nt * 16 + q4 * 4);
    qA01[nt] = cvt_pk((QtA[nt][0] + b4[0]) * scale, (QtA[nt][1] + b4[1]) * scale);
    qA23[nt] = cvt_pk((QtA[nt][2] + b4[2]) * scale, (QtA[nt][3] + b4[3]) * scale);
    qB01[nt] = cvt_pk((QtB[nt][0] + b4[0]) * scale, (QtB[nt][1] + b4[1]) * scale);
    qB23[nt] = cvt_pk((QtB[nt][2] + b4[2]) * scale, (QtB[nt][3] + b4[3]) * scale);
  }

  const int sa = ((2 * q4) & 3) * 16 + lc;
  const int sb = ((2 * q4 + 1) & 3) * 16 + lc;
  const bool hi = (q4 >= 2);

  bf16x8 bQA[4], bQB[4];
  #pragma unroll
  for (int kc = 0; kc < 4; ++kc) {
    bQA[kc] = xpose(qA01[2 * kc], qA01[2 * kc + 1], qA23[2 * kc], qA23[2 * kc + 1], sa, sb, hi);
    bQB[kc] = xpose(qB01[2 * kc], qB01[2 * kc + 1], qB23[2 * kc], qB23[2 * kc + 1], sa, sb, hi);
  }

  f32x4 SA[16], SB[16];
  #pragma unroll
  for (int jt = 0; jt < 16; ++jt) { SA[jt] = Z4; SB[jt] = Z4; }
  #pragma unroll
  for (int kc = 0; kc < 4; ++kc) {
    #pragma unroll
    for (int jt = 0; jt < 16; ++jt) {
      bf16x8 bK = *(const bf16x8*)(Kb + (jt * 16 + lc) * 128 + (((kc * 4 + q4) ^ lc) << 3));
      SA[jt] = MFMA(bK, bQA[kc], SA[jt]);
      SB[jt] = MFMA(bK, bQB[kc], SB[jt]);
    }
  }

  unsigned int pA01[16], pA23[16], pB01[16], pB23[16];
  softmax_pack(SA, pA01, pA23);
  softmax_pack(SB, pB01, pB23);

  bf16x8 aPA[8], aPB[8];
  #pragma unroll
  for (int kc = 0; kc < 8; ++kc) {
    aPA[kc] = xpose(pA01[2 * kc], pA01[2 * kc + 1], pA23[2 * kc], pA23[2 * kc + 1], sa, sb, hi);
    aPB[kc] = xpose(pB01[2 * kc], pB01[2 * kc + 1], pB23[2 * kc], pB23[2 * kc + 1], sa, sb, hi);
  }

  f32x4 CA[8], CB[8];
  #pragma unroll
  for (int nt = 0; nt < 8; ++nt) { CA[nt] = Z4; CB[nt] = Z4; }
  #pragma unroll
  for (int kc = 0; kc < 8; ++kc) {
    #pragma unroll
    for (int nt = 0; nt < 8; ++nt) {
      bf16x8 bV = *(const bf16x8*)(V2t + (nt * 16 + lc) * 256 + (((kc * 4 + q4) ^ lc) << 3));
      CA[nt] = MFMA(bV, aPA[kc], CA[nt]);
      CB[nt] = MFMA(bV, aPB[kc], CB[nt]);
    }
  }

  f32x4 VA[8], VB[8];
  #pragma unroll
  for (int nt = 0; nt < 8; ++nt) { VA[nt] = Z4; VB[nt] = Z4; }
  #pragma unroll
  for (int kc = 0; kc < 4; ++kc) {
    #pragma unroll
    for (int nt = 0; nt < 8; ++nt) {
      bf16x8 aW = *(const bf16x8*)(Wv1B + (nt * 16 + lc) * 128 + kc * 32 + q4 * 8);
      VA[nt] = MFMA(aW, aEA[kc], VA[nt]);
      VB[nt] = MFMA(aW, aEB[kc], VB[nt]);
    }
  }
  #pragma unroll
  for (int nt = 0; nt < 8; ++nt) {
    f32x4 b4 = *(const f32x4*)(bv1 + nt * 16 + q4 * 4);
    #pragma unroll
    for (int r = 0; r < 4; ++r) {
      CA[nt][r] *= (VA[nt][r] + b4[r]);
      CB[nt][r] *= (VB[nt][r] + b4[r]);
    }
  }

  unsigned int cA01[8], cA23[8], cB01[8], cB23[8];
  #pragma unroll
  for (int nt = 0; nt < 8; ++nt) {
    cA01[nt] = cvt_pk(CA[nt][0], CA[nt][1]);
    cA23[nt] = cvt_pk(CA[nt][2], CA[nt][3]);
    cB01[nt] = cvt_pk(CB[nt][0], CB[nt][1]);
    cB23[nt] = cvt_pk(CB[nt][2], CB[nt][3]);
  }
  bf16x8 aCA[4], aCB[4];
  #pragma unroll
  for (int kc = 0; kc < 4; ++kc) {
    aCA[kc] = xpose(cA01[2 * kc], cA01[2 * kc + 1], cA23[2 * kc], cA23[2 * kc + 1], sa, sb, hi);
    aCB[kc] = xpose(cB01[2 * kc], cB01[2 * kc + 1], cB23[2 * kc], cB23[2 * kc + 1], sa, sb, hi);
  }

  f32x4 OA[8], OB[8];
  #pragma unroll
  for (int n = 0; n < 8; ++n) { OA[n] = Z4; OB[n] = Z4; }
  #pragma unroll
  for (int kc = 0; kc < 4; ++kc) {
    #pragma unroll
    for (int n = 0; n < 8; ++n) {
      bf16x8 bw = *(const bf16x8*)(WoB + (n * 16 + lc) * 128 + kc * 32 + q4 * 8);
      OA[n] = MFMA(aCA[kc], bw, OA[n]);
      OB[n] = MFMA(aCB[kc], bw, OB[n]);
    }
  }
  #pragma unroll
  for (int n = 0; n < 8; ++n) {
    const float bov = bo[n * 16 + lc];
    #pragma unroll
    for (int r = 0; r < 4; ++r) {
      const int ia = jA + q4 * 4 + r;
      const int ib = jB + q4 * 4 + r;
      out[(((size_t)(bb * 256 + ia)) * 256 + lb) * 128 + n * 16 + lc] = OA[n][r] + bov;
      out[(((size_t)(bb * 256 + ib)) * 256 + lb) * 128 + n * 16 + lc] = OB[n][r] + bov;
    }
  }
}

extern "C" void kernel_launch(void* const* d_in, const int* in_sizes, int n_in,
                              void* d_out, int out_size, void* d_ws, size_t ws_size,
                              hipStream_t stream) {
  const float* ef   = (const float*)d_in[0];
  const float* Wq   = (const float*)d_in[1];
  const float* bqp  = (const float*)d_in[2];
  const float* Wk   = (const float*)d_in[3];
  const float* bkp  = (const float*)d_in[4];
  const float* Wv1  = (const float*)d_in[5];
  const float* bv1p = (const float*)d_in[6];
  const float* Wv2  = (const float*)d_in[7];
  const float* bv2p = (const float*)d_in[8];
  const float* Wo   = (const float*)d_in[9];
  const float* bop  = (const float*)d_in[10];
  unsigned short* wbf = (unsigned short*)d_ws;   // 5 * 128*128 bf16 = 160 KB

  cvt_weights<<<64, 256, 0, stream>>>(Wq, Wk, Wv1, Wv2, Wo, wbf);

  edge_attn_v6<<<512, 512, 0, stream>>>(ef, wbf, bqp, bkp, bv1p, bv2p, bop,
                                        (float*)d_out);
  if (hipGetLastError() != hipSuccess) {
    // 160 KB LDS launch rejected — fall back to the proven round-4 kernel.
    edge_attn_r4<<<512, 512, 0, stream>>>(ef, wbf, bqp, bkp, bv1p, bv2p, bop,
                                          (float*)d_out);
  }
}